// Round 1
// 2858.181 us; speedup vs baseline: 1.2872x; 1.2872x over previous
//
#include <hip/hip_runtime.h>
#include <math.h>

#define NN   50000
#define EGE  800000
#define DIM  128
#define DFF  256
#define HH   8

// ---- workspace layout (float element offsets) ----
#define Q_OFF     0ul
#define K_OFF     6400000ul
#define V_OFF     12800000ul
#define HA_OFF    19200000ul
#define S_OFF     25600000ul       // s per (edge, head): EGE*8
#define STAT_OFF  32000000ul       // 8 x 128 stat accumulators (sum/sumsq for e1,h1,e2,h2)
#define SCALE_OFF 32001024ul       // 8 x 128 scale/shift
#define CNT_OFF   32002048ul       // int counts[50000]
#define OFFS_OFF  32052096ul       // int offsets[50001]
#define CUR_OFF   32102144ul       // int cursor[50000]
#define BSUM_OFF  32152192ul       // int bsums[64]
#define CSR_OFF   32152256ul       // int csr[800000]
// total ~32.95M floats ~ 132 MB

typedef __attribute__((ext_vector_type(8))) _Float16 half8;
typedef __attribute__((ext_vector_type(4))) float f32x4;

// fp16 MFMA-fragment-ordered FFN weights (converted each launch by k_prep)
__device__ _Float16 g_Wh1h[32768];  // K=128, N=256
__device__ _Float16 g_Wh2h[32768];  // K=256, N=128
__device__ _Float16 g_We1h[32768];
__device__ _Float16 g_We2h[32768];

__device__ __forceinline__ float4 ld4(const float* p) { return *(const float4*)p; }

__device__ __forceinline__ void fma_quad(float4& acc, const float4 a,
    const float4 w0, const float4 w1, const float4 w2, const float4 w3)
{
    acc.x = fmaf(a.x, w0.x, acc.x); acc.y = fmaf(a.x, w0.y, acc.y);
    acc.z = fmaf(a.x, w0.z, acc.z); acc.w = fmaf(a.x, w0.w, acc.w);
    acc.x = fmaf(a.y, w1.x, acc.x); acc.y = fmaf(a.y, w1.y, acc.y);
    acc.z = fmaf(a.y, w1.z, acc.z); acc.w = fmaf(a.y, w1.w, acc.w);
    acc.x = fmaf(a.z, w2.x, acc.x); acc.y = fmaf(a.z, w2.y, acc.y);
    acc.z = fmaf(a.z, w2.z, acc.z); acc.w = fmaf(a.z, w2.w, acc.w);
    acc.x = fmaf(a.w, w3.x, acc.x); acc.y = fmaf(a.w, w3.y, acc.y);
    acc.z = fmaf(a.w, w3.z, acc.z); acc.w = fmaf(a.w, w3.w, acc.w);
}

// ---------------- weight prep: fp32 (KxN row-major) -> fp16 B-fragment order ----------------
// Fragment layout for v_mfma_f32_16x16x32_f16 B operand:
//   lane l holds col n = 16*ntile + (l&15), k = 32*ks + 8*(l>>4) + j   (j = 0..7 contiguous)
// Stored as [ntile][ks][lane][8] -> one 16B load per fragment per lane.
__global__ __launch_bounds__(256) void k_prep(
    const float* __restrict__ Wh1, const float* __restrict__ Wh2,
    const float* __restrict__ We1, const float* __restrict__ We2)
{
    int idx = blockIdx.x * 256 + threadIdx.x;   // 0..16383
    int which = idx >> 12;                      // 4096 threads per weight
    int r = idx & 4095;
    const float* W; _Float16* O; int K, N;
    switch (which) {
        case 0:  W = Wh1; O = g_Wh1h; K = 128; N = 256; break;
        case 1:  W = Wh2; O = g_Wh2h; K = 256; N = 128; break;
        case 2:  W = We1; O = g_We1h; K = 128; N = 256; break;
        default: W = We2; O = g_We2h; K = 256; N = 128; break;
    }
    int lane = r & 63;
    int fid  = r >> 6;            // fragment id = ntile*(K/32) + ks
    int ksn  = K >> 5;
    int ks   = fid % ksn;
    int ntile = fid / ksn;
    int n  = (ntile << 4) + (lane & 15);
    int kb = (ks << 5) + ((lane >> 4) << 3);
    half8 v;
    #pragma unroll
    for (int j = 0; j < 8; j++)
        v[j] = (_Float16)W[(size_t)(kb + j) * N + n];
    *(half8*)&O[(size_t)r * 8] = v;
}

// ---------------- QKV projection: 64-row tiles ----------------
__global__ __launch_bounds__(256) void k_qkv(
    const float* __restrict__ h,
    const float* __restrict__ WQ, const float* __restrict__ bQ,
    const float* __restrict__ WK, const float* __restrict__ bK,
    const float* __restrict__ WV, const float* __restrict__ bV,
    float* __restrict__ Qo, float* __restrict__ Ko, float* __restrict__ Vo)
{
    __shared__ float As[64 * DIM];
    const int t = threadIdx.x;
    const int cg = t & 31, rg = t >> 5;   // 32 col groups (4 cols), 8 row groups (8 rows)
    const int c0 = cg * 4;
    const int row0 = blockIdx.x * 64;

    #pragma unroll
    for (int i = 0; i < 8; i++) {
        int idx = t + 256 * i; int r = idx >> 5; int c4 = (idx & 31) * 4;
        int gr = row0 + r;
        float4 v = make_float4(0.f, 0.f, 0.f, 0.f);
        if (gr < NN) v = ld4(&h[(size_t)gr * DIM + c4]);
        *(float4*)&As[r * DIM + c4] = v;
    }
    __syncthreads();

    #pragma unroll
    for (int m = 0; m < 3; m++) {
        const float* __restrict__ W = (m == 0) ? WQ : ((m == 1) ? WK : WV);
        const float* __restrict__ bb = (m == 0) ? bQ : ((m == 1) ? bK : bV);
        float* __restrict__ O = (m == 0) ? Qo : ((m == 1) ? Ko : Vo);
        float4 bv = ld4(&bb[c0]);
        float4 acc[8];
        #pragma unroll
        for (int i = 0; i < 8; i++) acc[i] = bv;
        for (int k = 0; k < DIM; k += 4) {
            float4 w0 = ld4(&W[(k + 0) * DIM + c0]);
            float4 w1 = ld4(&W[(k + 1) * DIM + c0]);
            float4 w2 = ld4(&W[(k + 2) * DIM + c0]);
            float4 w3 = ld4(&W[(k + 3) * DIM + c0]);
            #pragma unroll
            for (int i = 0; i < 8; i++) {
                float4 a = *(const float4*)&As[(rg * 8 + i) * DIM + k];
                fma_quad(acc[i], a, w0, w1, w2, w3);
            }
        }
        #pragma unroll
        for (int i = 0; i < 8; i++) {
            int gr = row0 + rg * 8 + i;
            if (gr < NN) *(float4*)&O[(size_t)gr * DIM + c0] = acc[i];
        }
    }
}

// ---------------- Edge pass A: Ee, score, s, e1pre, e1 stats, dst histogram ----------------
__global__ __launch_bounds__(256) void k_edgeA(
    const float* __restrict__ e, const int* __restrict__ src, const int* __restrict__ dst,
    const float* __restrict__ Qm, const float* __restrict__ Km,
    const float* __restrict__ WE, const float* __restrict__ bE,
    const float* __restrict__ WOe, const float* __restrict__ bOe,
    float* __restrict__ e1pre, float* __restrict__ s_ws,
    float* __restrict__ ssum, float* __restrict__ ssq, int* __restrict__ counts)
{
    __shared__ float Ae[32 * DIM];
    __shared__ float Sc[32 * DIM];
    __shared__ float lsum[DIM], lsq[DIM];
    __shared__ int sdst[32], ssrc[32];
    const int t = threadIdx.x;
    const int cg = t & 31, rg = t >> 5;  // rows rg*4 .. rg*4+3
    const int c0 = cg * 4;
    const int e0 = blockIdx.x * 32;

    if (t < DIM) { lsum[t] = 0.f; lsq[t] = 0.f; }
    if (t < 32) { sdst[t] = dst[e0 + t]; ssrc[t] = src[e0 + t]; }
    #pragma unroll
    for (int i = 0; i < 4; i++) {
        int idx = t + 256 * i; int r = idx >> 5; int c4 = (idx & 31) * 4;
        *(float4*)&Ae[r * DIM + c4] = ld4(&e[(size_t)(e0 + r) * DIM + c4]);
    }
    __syncthreads();

    // GEMM1: Ee = Ae @ WE + bE
    float4 acc[4];
    {
        float4 bv = ld4(&bE[c0]);
        #pragma unroll
        for (int i = 0; i < 4; i++) acc[i] = bv;
        for (int k = 0; k < DIM; k += 4) {
            float4 w0 = ld4(&WE[(k + 0) * DIM + c0]);
            float4 w1 = ld4(&WE[(k + 1) * DIM + c0]);
            float4 w2 = ld4(&WE[(k + 2) * DIM + c0]);
            float4 w3 = ld4(&WE[(k + 3) * DIM + c0]);
            #pragma unroll
            for (int i = 0; i < 4; i++) {
                float4 a = *(const float4*)&Ae[(rg * 4 + i) * DIM + k];
                fma_quad(acc[i], a, w0, w1, w2, w3);
            }
        }
    }
    // score = K[src]*Q[dst]*0.25*Ee ; per-head sums -> s
    #pragma unroll
    for (int i = 0; i < 4; i++) {
        int r = rg * 4 + i;
        int sn = ssrc[r], dn = sdst[r];
        float4 kk = ld4(&Km[(size_t)sn * DIM + c0]);
        float4 qq = ld4(&Qm[(size_t)dn * DIM + c0]);
        float4 sc;
        sc.x = kk.x * qq.x * 0.25f * acc[i].x;
        sc.y = kk.y * qq.y * 0.25f * acc[i].y;
        sc.z = kk.z * qq.z * 0.25f * acc[i].z;
        sc.w = kk.w * qq.w * 0.25f * acc[i].w;
        *(float4*)&Sc[r * DIM + c0] = sc;
        float part = sc.x + sc.y + sc.z + sc.w;
        part += __shfl_xor(part, 1);
        part += __shfl_xor(part, 2);   // 4 col-groups of one head share cg bits 0..1
        if ((cg & 3) == 0) {
            float sv = expf(fminf(fmaxf(part, -5.f), 5.f));
            s_ws[(size_t)(e0 + r) * HH + (cg >> 2)] = sv;
        }
    }
    if (t < 32) atomicAdd(&counts[sdst[t]], 1);
    __syncthreads();

    // GEMM2: e1 = e + Sc @ WOe + bOe  (+stats)
    float4 acc2[4];
    {
        float4 bv = ld4(&bOe[c0]);
        #pragma unroll
        for (int i = 0; i < 4; i++) acc2[i] = bv;
        for (int k = 0; k < DIM; k += 4) {
            float4 w0 = ld4(&WOe[(k + 0) * DIM + c0]);
            float4 w1 = ld4(&WOe[(k + 1) * DIM + c0]);
            float4 w2 = ld4(&WOe[(k + 2) * DIM + c0]);
            float4 w3 = ld4(&WOe[(k + 3) * DIM + c0]);
            #pragma unroll
            for (int i = 0; i < 4; i++) {
                float4 a = *(const float4*)&Sc[(rg * 4 + i) * DIM + k];
                fma_quad(acc2[i], a, w0, w1, w2, w3);
            }
        }
    }
    float ps0 = 0, ps1 = 0, ps2 = 0, ps3 = 0, pq0 = 0, pq1 = 0, pq2 = 0, pq3 = 0;
    #pragma unroll
    for (int i = 0; i < 4; i++) {
        int r = rg * 4 + i;
        float4 er = *(const float4*)&Ae[r * DIM + c0];
        float4 y;
        y.x = acc2[i].x + er.x; y.y = acc2[i].y + er.y;
        y.z = acc2[i].z + er.z; y.w = acc2[i].w + er.w;
        *(float4*)&e1pre[(size_t)(e0 + r) * DIM + c0] = y;
        ps0 += y.x; pq0 += y.x * y.x;
        ps1 += y.y; pq1 += y.y * y.y;
        ps2 += y.z; pq2 += y.z * y.z;
        ps3 += y.w; pq3 += y.w * y.w;
    }
    atomicAdd(&lsum[c0 + 0], ps0); atomicAdd(&lsq[c0 + 0], pq0);
    atomicAdd(&lsum[c0 + 1], ps1); atomicAdd(&lsq[c0 + 1], pq1);
    atomicAdd(&lsum[c0 + 2], ps2); atomicAdd(&lsq[c0 + 2], pq2);
    atomicAdd(&lsum[c0 + 3], ps3); atomicAdd(&lsq[c0 + 3], pq3);
    __syncthreads();
    if (t < DIM) { atomicAdd(&ssum[t], lsum[t]); atomicAdd(&ssq[t], lsq[t]); }
}

// ---------------- CSR build: scan + scatter ----------------
__global__ __launch_bounds__(256) void k_scan1(int* __restrict__ data, int* __restrict__ bsums, int n)
{
    __shared__ int sd[256];
    const int t = threadIdx.x;
    const int base = blockIdx.x * 1024 + t * 4;
    int v0 = (base + 0 < n) ? data[base + 0] : 0;
    int v1 = (base + 1 < n) ? data[base + 1] : 0;
    int v2 = (base + 2 < n) ? data[base + 2] : 0;
    int v3 = (base + 3 < n) ? data[base + 3] : 0;
    int tsum = v0 + v1 + v2 + v3;
    sd[t] = tsum;
    __syncthreads();
    for (int off = 1; off < 256; off <<= 1) {
        int x = (t >= off) ? sd[t - off] : 0;
        __syncthreads();
        sd[t] += x;
        __syncthreads();
    }
    int run = sd[t] - tsum;  // exclusive prefix
    if (base + 0 < n) { data[base + 0] = run; } run += v0;
    if (base + 1 < n) { data[base + 1] = run; } run += v1;
    if (base + 2 < n) { data[base + 2] = run; } run += v2;
    if (base + 3 < n) { data[base + 3] = run; }
    if (t == 255) bsums[blockIdx.x] = sd[255];
}

__global__ void k_scan2(int* __restrict__ bsums, int nb)
{
    if (threadIdx.x == 0) {
        int run = 0;
        for (int i = 0; i < nb; i++) { int x = bsums[i]; bsums[i] = run; run += x; }
    }
}

__global__ void k_scan3(const int* __restrict__ data, const int* __restrict__ bsums,
                        int* __restrict__ offsets, int* __restrict__ cursor, int n, int total)
{
    int i = blockIdx.x * 256 + threadIdx.x;
    if (i < n) {
        int o = data[i] + bsums[i >> 10];
        offsets[i] = o; cursor[i] = o;
    }
    if (i == 0) offsets[n] = total;
}

__global__ void k_scatter(const int* __restrict__ dst, int* __restrict__ cursor, int* __restrict__ csr)
{
    int eid = blockIdx.x * 256 + threadIdx.x;
    if (eid < EGE) {
        int d = dst[eid];
        int p = atomicAdd(&cursor[d], 1);
        csr[p] = eid;
    }
}

// ---------------- per-node attention aggregate (one wave per node) ----------------
__global__ __launch_bounds__(256) void k_attn(
    const int* __restrict__ offsets, const int* __restrict__ csr,
    const int* __restrict__ src, const float* __restrict__ s_ws,
    const float* __restrict__ Vm, float* __restrict__ ha)
{
    const int wid = threadIdx.x >> 6;
    const int lane = threadIdx.x & 63;
    const int node = blockIdx.x * 4 + wid;
    if (node >= NN) return;
    const int beg = offsets[node], end = offsets[node + 1];
    const int hidx = lane >> 3;      // head of cols lane*2, lane*2+1
    const int c = lane * 2;
    float ax = 0.f, ay = 0.f, z = 0.f;
    for (int i = beg; i < end; i++) {
        int eid = csr[i];
        float sv = s_ws[(size_t)eid * HH + hidx];
        int sn = src[eid];
        float2 v2 = *(const float2*)&Vm[(size_t)sn * DIM + c];
        ax = fmaf(v2.x, sv, ax); ay = fmaf(v2.y, sv, ay);
        z += sv;
    }
    float inv = 1.f / (z + 1e-6f);
    float2 o; o.x = ax * inv; o.y = ay * inv;
    *(float2*)&ha[(size_t)node * DIM + c] = o;
}

// ---------------- h1 = h + h_attn @ WOh + bOh (+stats) ----------------
__global__ __launch_bounds__(256) void k_h1(
    const float* __restrict__ ha, const float* __restrict__ h,
    const float* __restrict__ W, const float* __restrict__ b,
    float* __restrict__ out, float* __restrict__ ssum, float* __restrict__ ssq)
{
    __shared__ float As[32 * DIM];
    __shared__ float lsum[DIM], lsq[DIM];
    const int t = threadIdx.x;
    const int cg = t & 31, rg = t >> 5;
    const int c0 = cg * 4;
    const int row0 = blockIdx.x * 32;
    if (t < DIM) { lsum[t] = 0.f; lsq[t] = 0.f; }
    #pragma unroll
    for (int i = 0; i < 4; i++) {
        int idx = t + 256 * i; int r = idx >> 5; int c4 = (idx & 31) * 4;
        int gr = row0 + r;
        float4 v = make_float4(0.f, 0.f, 0.f, 0.f);
        if (gr < NN) v = ld4(&ha[(size_t)gr * DIM + c4]);
        *(float4*)&As[r * DIM + c4] = v;
    }
    __syncthreads();
    float4 acc[4];
    float4 bv = ld4(&b[c0]);
    #pragma unroll
    for (int i = 0; i < 4; i++) acc[i] = bv;
    for (int k = 0; k < DIM; k += 4) {
        float4 w0 = ld4(&W[(k + 0) * DIM + c0]);
        float4 w1 = ld4(&W[(k + 1) * DIM + c0]);
        float4 w2 = ld4(&W[(k + 2) * DIM + c0]);
        float4 w3 = ld4(&W[(k + 3) * DIM + c0]);
        #pragma unroll
        for (int i = 0; i < 4; i++) {
            float4 a = *(const float4*)&As[(rg * 4 + i) * DIM + k];
            fma_quad(acc[i], a, w0, w1, w2, w3);
        }
    }
    float ps0 = 0, ps1 = 0, ps2 = 0, ps3 = 0, pq0 = 0, pq1 = 0, pq2 = 0, pq3 = 0;
    #pragma unroll
    for (int i = 0; i < 4; i++) {
        int gr = row0 + rg * 4 + i;
        if (gr < NN) {
            float4 hr = ld4(&h[(size_t)gr * DIM + c0]);
            float4 y;
            y.x = acc[i].x + hr.x; y.y = acc[i].y + hr.y;
            y.z = acc[i].z + hr.z; y.w = acc[i].w + hr.w;
            *(float4*)&out[(size_t)gr * DIM + c0] = y;
            ps0 += y.x; pq0 += y.x * y.x;
            ps1 += y.y; pq1 += y.y * y.y;
            ps2 += y.z; pq2 += y.z * y.z;
            ps3 += y.w; pq3 += y.w * y.w;
        }
    }
    atomicAdd(&lsum[c0 + 0], ps0); atomicAdd(&lsq[c0 + 0], pq0);
    atomicAdd(&lsum[c0 + 1], ps1); atomicAdd(&lsq[c0 + 1], pq1);
    atomicAdd(&lsum[c0 + 2], ps2); atomicAdd(&lsq[c0 + 2], pq2);
    atomicAdd(&lsum[c0 + 3], ps3); atomicAdd(&lsq[c0 + 3], pq3);
    __syncthreads();
    if (t < DIM) { atomicAdd(&ssum[t], lsum[t]); atomicAdd(&ssq[t], lsq[t]); }
}

// ---------------- finalize BN stats -> scale/shift ----------------
__global__ void k_finalize(const float* __restrict__ ssum, const float* __restrict__ ssq,
                           float invn, const float* __restrict__ g, const float* __restrict__ b,
                           float* __restrict__ scale, float* __restrict__ shift)
{
    int c = threadIdx.x;
    float mu = ssum[c] * invn;
    float var = fmaxf(ssq[c] * invn - mu * mu, 0.f);
    float rstd = rsqrtf(var + 1e-5f);
    float sc = g[c] * rstd;
    scale[c] = sc;
    shift[c] = fmaf(-mu, sc, b[c]);
}

// ---------------- FFN via fp16 MFMA: Y = BN(X) + relu(BN(X)@W1+b1)@W2+b2, in place, +stats ----
// 32 rows/block, 256 threads = 4 waves. MFMA v_mfma_f32_16x16x32_f16:
//   A: lane l holds row (l&15), k = 8*(l>>4)+j (j=0..7 contiguous)
//   B: lane l holds col (l&15), same k mapping
//   C/D: lane l holds col (l&15), rows 4*(l>>4)+reg    [m89-verified]
#define LDA_XN 132   // fp32 Xn row stride (2-way bank aliasing: free)
#define LDA_U  264   // fp16 U row stride

__global__ __launch_bounds__(256) void k_ffn_mfma(
    float* __restrict__ X, int M, int sel,
    const float* __restrict__ scale, const float* __restrict__ shift,
    const float* __restrict__ b1v, const float* __restrict__ b2v,
    float* __restrict__ ssum, float* __restrict__ ssq)
{
    __shared__ float   Xn[32 * LDA_XN];   // 16896 B
    __shared__ _Float16 Us[32 * LDA_U];   // 16896 B
    const int t = threadIdx.x;
    const int w = t >> 6, l = t & 63;
    const int lw = l >> 4, ln = l & 15;
    const int row0 = blockIdx.x * 32;
    const _Float16* __restrict__ W1f = sel ? g_Wh1h : g_We1h;
    const _Float16* __restrict__ W2f = sel ? g_Wh2h : g_We2h;

    // phase 1: load X, apply BN scale/shift -> Xn (fp32)
    #pragma unroll
    for (int i = 0; i < 4; i++) {
        int idx = t + 256 * i; int r = idx >> 5; int c4 = (idx & 31) * 4;
        int gr = row0 + r;
        float4 v = make_float4(0.f, 0.f, 0.f, 0.f);
        if (gr < M) v = ld4(&X[(size_t)gr * DIM + c4]);
        float4 sc = ld4(&scale[c4]); float4 sh = ld4(&shift[c4]);
        v.x = fmaf(v.x, sc.x, sh.x); v.y = fmaf(v.y, sc.y, sh.y);
        v.z = fmaf(v.z, sc.z, sh.z); v.w = fmaf(v.w, sc.w, sh.w);
        *(float4*)&Xn[r * LDA_XN + c4] = v;
    }
    __syncthreads();

    // phase 2: U = relu(Xn @ W1 + b1), wave w owns cols 64w..64w+63
    {
        half8 a[2][4];
        #pragma unroll
        for (int m = 0; m < 2; m++)
        #pragma unroll
        for (int ks = 0; ks < 4; ks++) {
            const float* p = &Xn[(16 * m + ln) * LDA_XN + 32 * ks + 8 * lw];
            float4 lo = *(const float4*)p;
            float4 hi = *(const float4*)(p + 4);
            half8 av;
            av[0] = (_Float16)lo.x; av[1] = (_Float16)lo.y;
            av[2] = (_Float16)lo.z; av[3] = (_Float16)lo.w;
            av[4] = (_Float16)hi.x; av[5] = (_Float16)hi.y;
            av[6] = (_Float16)hi.z; av[7] = (_Float16)hi.w;
            a[m][ks] = av;
        }
        #pragma unroll
        for (int nt = 0; nt < 4; nt++) {
            int ntile = 4 * w + nt;
            f32x4 c0 = {0.f, 0.f, 0.f, 0.f}, c1 = {0.f, 0.f, 0.f, 0.f};
            #pragma unroll
            for (int ks = 0; ks < 4; ks++) {
                half8 b = *(const half8*)&W1f[(size_t)((ntile * 4 + ks) * 64 + l) * 8];
                c0 = __builtin_amdgcn_mfma_f32_16x16x32_f16(a[0][ks], b, c0, 0, 0, 0);
                c1 = __builtin_amdgcn_mfma_f32_16x16x32_f16(a[1][ks], b, c1, 0, 0, 0);
            }
            int col = ntile * 16 + ln;
            float bias = b1v[col];
            #pragma unroll
            for (int r = 0; r < 4; r++) {
                float u0 = fmaxf(c0[r] + bias, 0.f);
                float u1 = fmaxf(c1[r] + bias, 0.f);
                Us[(4 * lw + r) * LDA_U + col] = (_Float16)u0;
                Us[(16 + 4 * lw + r) * LDA_U + col] = (_Float16)u1;
            }
        }
    }
    __syncthreads();

    // phase 3: Y = Xn + U @ W2 + b2, wave w owns cols 32w..32w+31
    {
        half8 a2[2][8];
        #pragma unroll
        for (int m = 0; m < 2; m++)
        #pragma unroll
        for (int ks = 0; ks < 8; ks++)
            a2[m][ks] = *(const half8*)&Us[(16 * m + ln) * LDA_U + 32 * ks + 8 * lw];
        #pragma unroll
        for (int nt = 0; nt < 2; nt++) {
            int ntile = 2 * w + nt;
            f32x4 c0 = {0.f, 0.f, 0.f, 0.f}, c1 = {0.f, 0.f, 0.f, 0.f};
            #pragma unroll
            for (int ks = 0; ks < 8; ks++) {
                half8 b = *(const half8*)&W2f[(size_t)((ntile * 8 + ks) * 64 + l) * 8];
                c0 = __builtin_amdgcn_mfma_f32_16x16x32_f16(a2[0][ks], b, c0, 0, 0, 0);
                c1 = __builtin_amdgcn_mfma_f32_16x16x32_f16(a2[1][ks], b, c1, 0, 0, 0);
            }
            int col = ntile * 16 + ln;
            float bias = b2v[col];
            float s = 0.f, q = 0.f;
            #pragma unroll
            for (int r = 0; r < 4; r++) {
                int r0 = 4 * lw + r, r1 = 16 + 4 * lw + r;
                float y0 = c0[r] + bias + Xn[r0 * LDA_XN + col];
                float y1 = c1[r] + bias + Xn[r1 * LDA_XN + col];
                int g0 = row0 + r0, g1 = row0 + r1;
                if (g0 < M) { X[(size_t)g0 * DIM + col] = y0; s += y0; q += y0 * y0; }
                if (g1 < M) { X[(size_t)g1 * DIM + col] = y1; s += y1; q += y1 * y1; }
            }
            s += __shfl_xor(s, 16); s += __shfl_xor(s, 32);
            q += __shfl_xor(q, 16); q += __shfl_xor(q, 32);
            if (lw == 0) { atomicAdd(&ssum[col], s); atomicAdd(&ssq[col], q); }
        }
    }
}

// ---------------- final BN elementwise, in place ----------------
__global__ __launch_bounds__(256) void k_bnout(float* __restrict__ X,
    const float* __restrict__ scale, const float* __restrict__ shift, int M)
{
    size_t i4 = (size_t)blockIdx.x * 256 + threadIdx.x;
    size_t idx = i4 * 4;
    if (idx >= (size_t)M * DIM) return;
    int c4 = (int)(idx & (DIM - 1));
    float4 v = *(float4*)&X[idx];
    float4 sc = ld4(&scale[c4]); float4 sh = ld4(&shift[c4]);
    v.x = fmaf(v.x, sc.x, sh.x); v.y = fmaf(v.y, sc.y, sh.y);
    v.z = fmaf(v.z, sc.z, sh.z); v.w = fmaf(v.w, sc.w, sh.w);
    *(float4*)&X[idx] = v;
}

extern "C" void kernel_launch(void* const* d_in, const int* in_sizes, int n_in,
                              void* d_out, int out_size, void* d_ws, size_t ws_size,
                              hipStream_t stream)
{
    const float* h   = (const float*)d_in[0];
    const float* e   = (const float*)d_in[1];
    const int*   src = (const int*)d_in[2];
    const int*   dst = (const int*)d_in[3];
    const float* WQ  = (const float*)d_in[4];  const float* bQ  = (const float*)d_in[5];
    const float* WK  = (const float*)d_in[6];  const float* bK  = (const float*)d_in[7];
    const float* WV  = (const float*)d_in[8];  const float* bV  = (const float*)d_in[9];
    const float* WE  = (const float*)d_in[10]; const float* bE  = (const float*)d_in[11];
    const float* WOh = (const float*)d_in[12]; const float* bOh = (const float*)d_in[13];
    const float* WOe = (const float*)d_in[14]; const float* bOe = (const float*)d_in[15];
    const float* Wh1 = (const float*)d_in[16]; const float* bh1 = (const float*)d_in[17];
    const float* Wh2 = (const float*)d_in[18]; const float* bh2 = (const float*)d_in[19];
    const float* We1 = (const float*)d_in[20]; const float* be1 = (const float*)d_in[21];
    const float* We2 = (const float*)d_in[22]; const float* be2 = (const float*)d_in[23];
    const float* g1h = (const float*)d_in[24]; const float* g1e = (const float*)d_in[25];
    const float* g2h = (const float*)d_in[26]; const float* g2e = (const float*)d_in[27];
    const float* b1h = (const float*)d_in[28]; const float* b1e = (const float*)d_in[29];
    const float* b2h = (const float*)d_in[30]; const float* b2e = (const float*)d_in[31];

    float* out   = (float*)d_out;
    float* h_buf = out;                        // N x 128 (h1pre -> h2pre -> h_out)
    float* e_buf = out + (size_t)NN * DIM;     // E x 128 (e1pre -> e2pre -> e_out)

    float* ws = (float*)d_ws;
    float* Qm = ws + Q_OFF;
    float* Km = ws + K_OFF;
    float* Vm = ws + V_OFF;
    float* ha = ws + HA_OFF;
    float* s_ws = ws + S_OFF;
    float* st = ws + STAT_OFF;
    float* sum_e1 = st + 0;   float* sq_e1 = st + 128;
    float* sum_h1 = st + 256; float* sq_h1 = st + 384;
    float* sum_e2 = st + 512; float* sq_e2 = st + 640;
    float* sum_h2 = st + 768; float* sq_h2 = st + 896;
    float* scl = ws + SCALE_OFF;
    float* sc_e1 = scl + 0;   float* sh_e1 = scl + 128;
    float* sc_h1 = scl + 256; float* sh_h1 = scl + 384;
    float* sc_e2 = scl + 512; float* sh_e2 = scl + 640;
    float* sc_h2 = scl + 768; float* sh_h2 = scl + 896;
    int* counts  = (int*)(ws + CNT_OFF);
    int* offsets = (int*)(ws + OFFS_OFF);
    int* cursor  = (int*)(ws + CUR_OFF);
    int* bsums   = (int*)(ws + BSUM_OFF);
    int* csr     = (int*)(ws + CSR_OFF);

    // zero stats + scale/shift + counts (contiguous region)
    hipMemsetAsync(ws + STAT_OFF, 0, (size_t)(1024 + 1024 + 50048) * 4, stream);

    // fp16 fragment-ordered FFN weights (tiny; runs while nothing depends on it yet)
    k_prep<<<64, 256, 0, stream>>>(Wh1, Wh2, We1, We2);

    k_qkv<<<(NN + 63) / 64, 256, 0, stream>>>(h, WQ, bQ, WK, bK, WV, bV, Qm, Km, Vm);

    k_edgeA<<<EGE / 32, 256, 0, stream>>>(e, src, dst, Qm, Km, WE, bE, WOe, bOe,
                                          e_buf, s_ws, sum_e1, sq_e1, counts);

    const int NB1 = (NN + 1023) / 1024;  // 49
    k_scan1<<<NB1, 256, 0, stream>>>(counts, bsums, NN);
    k_scan2<<<1, 32, 0, stream>>>(bsums, NB1);
    k_scan3<<<(NN + 255) / 256, 256, 0, stream>>>(counts, bsums, offsets, cursor, NN, EGE);
    k_scatter<<<(EGE + 255) / 256, 256, 0, stream>>>(dst, cursor, csr);

    k_attn<<<(NN + 3) / 4, 256, 0, stream>>>(offsets, csr, src, s_ws, Vm, ha);

    k_h1<<<(NN + 31) / 32, 256, 0, stream>>>(ha, h, WOh, bOh, h_buf, sum_h1, sq_h1);

    k_finalize<<<1, 128, 0, stream>>>(sum_e1, sq_e1, 1.f / EGE, g1e, b1e, sc_e1, sh_e1);
    k_finalize<<<1, 128, 0, stream>>>(sum_h1, sq_h1, 1.f / NN, g1h, b1h, sc_h1, sh_h1);

    k_ffn_mfma<<<EGE / 32, 256, 0, stream>>>(e_buf, EGE, 0, sc_e1, sh_e1, be1, be2, sum_e2, sq_e2);
    k_ffn_mfma<<<(NN + 31) / 32, 256, 0, stream>>>(h_buf, NN, 1, sc_h1, sh_h1, bh1, bh2, sum_h2, sq_h2);

    k_finalize<<<1, 128, 0, stream>>>(sum_e2, sq_e2, 1.f / EGE, g2e, b2e, sc_e2, sh_e2);
    k_finalize<<<1, 128, 0, stream>>>(sum_h2, sq_h2, 1.f / NN, g2h, b2h, sc_h2, sh_h2);

    k_bnout<<<(int)(((size_t)EGE * DIM / 4 + 255) / 256), 256, 0, stream>>>(e_buf, sc_e2, sh_e2, EGE);
    k_bnout<<<(int)(((size_t)NN * DIM / 4 + 255) / 256), 256, 0, stream>>>(h_buf, sc_h2, sh_h2, NN);
}